// Round 2
// baseline (279.123 us; speedup 1.0000x reference)
//
#include <hip/hip_runtime.h>

#define EPS 1e-3f

// ---- ws layout (float offsets) ----
#define OFF_PGAP   0         // 65536  : per-(block,channel) gap partial sums [256][256]
#define OFF_A      65536     // 1024   : per-channel affine scale A[b][c]
#define OFF_BIAS   66560     // 16     : folded qkv bias [4][3]
#define OFF_QS     66576     // 16384  : spatial q  [4][4096]
#define OFF_KS     82960     // 16384  : spatial k
#define OFF_VS     99344     // 16384  : spatial v

// Grid-wide ticket barrier. Monotonic counter in module .data (NOT in poisoned ws,
// no memset needed). Strict ordering of barrier instances (stream-serialized
// launches + intra-launch phase order) means tickets come in exact groups of 256:
// ticket v belongs to instance v/256; wait until count reaches (v/256+1)*256.
// Device-scope atomics + __threadfence handle cross-XCD L2 non-coherence.
__device__ unsigned g_bar = 0u;

__device__ __forceinline__ void gridbar() {
    __syncthreads();                      // drains each wave's vmcnt before arrival
    if (threadIdx.x == 0) {
        __threadfence();                  // release: flush L2 to coherence point
        unsigned v = __hip_atomic_fetch_add(&g_bar, 1u, __ATOMIC_RELEASE,
                                            __HIP_MEMORY_SCOPE_AGENT);
        unsigned target = (v & ~255u) + 256u;
        unsigned tries = 0;
        while (__hip_atomic_load(&g_bar, __ATOMIC_ACQUIRE,
                                 __HIP_MEMORY_SCOPE_AGENT) < target) {
            __builtin_amdgcn_s_sleep(1);
            if (++tries > 20000000u) break;   // hang safety valve (~0.5s)
        }
        __threadfence();                  // acquire: invalidate stale L1/L2
    }
    __syncthreads();
}

// One persistent kernel, 256 blocks (1/CU, all co-resident) x 512 threads.
// Phase 0: gap partials + weight L3-warm
// Phase 1: full middle stage on 4 blocks (others prefetch phase-2 x from L3)
// Phase 2: qkv = (x*A + B) @ w_qkv, wave-per-pixel
// Phase 3: spatial attention + output
__global__ __launch_bounds__(512) void mega(
    const float* __restrict__ x,
    const float* __restrict__ cag, const float* __restrict__ cab,
    const float* __restrict__ cam, const float* __restrict__ cav,
    const float* __restrict__ wq, const float* __restrict__ wk,
    const float* __restrict__ wv, const float* __restrict__ wp,
    const float* __restrict__ bng, const float* __restrict__ bnb,
    const float* __restrict__ bnm, const float* __restrict__ bnv,
    const float* __restrict__ wqkv,
    float* __restrict__ ws, float* __restrict__ out)
{
    __shared__ float4 s4[2048];   // 32KB: phase0 gap partials(512) / phase3 skv(2048)
    __shared__ float  sA[6144];   // 24KB: phase1 matmul partials / phase3 pden+pnum
    __shared__ float  sB[2576];   // 10KB: phase1 vectors+swqkv / phase3 rmax,rmin

    float* pgap = ws + OFF_PGAP;
    float* Aw   = ws + OFF_A;
    float* bias = ws + OFF_BIAS;
    float* qs   = ws + OFF_QS;
    float* ks   = ws + OFF_KS;
    float* vs   = ws + OFF_VS;

    int blk = blockIdx.x;             // 0..255
    int t = threadIdx.x;              // 0..511
    int lane = t & 63, sub = t >> 6;  // sub = wave id (wave-uniform)

    // ============ Phase 0: gap partials (+ L3 warm of phase-1 operands) ============
    {
        if (t < 256) {   // 4KB weight slice per block -> all of wq/wk/wv/wp into L3
            const float* wmat = (blk < 64) ? wq : (blk < 128) ? wk
                              : (blk < 192) ? wv : wp;
            float4 w4 = *(const float4*)(wmat + (size_t)(blk & 63) * 1024 + 4 * t);
            asm volatile("" :: "v"(w4.x), "v"(w4.y), "v"(w4.z), "v"(w4.w));
        }
        if (blk == 1 && t < 256) {
            float z = bng[t] + bnb[t] + bnm[t] + bnv[t];
            asm volatile("" :: "v"(z));
        }
        if (blk == 2 && t < 256) {
            float z = cag[t] + cab[t] + cam[t] + cav[t];
            asm volatile("" :: "v"(z));
        }
        // 64 pixels per block: 8 waves x 8 pixels, float4 channel quads
        const float* xp = x + ((size_t)blk * 64 + sub * 8) * 256 + 4 * lane;
        float4 s = make_float4(0.f, 0.f, 0.f, 0.f);
        #pragma unroll
        for (int u = 0; u < 8; ++u) {
            float4 v = *(const float4*)(xp + (size_t)u * 256);
            s.x += v.x; s.y += v.y; s.z += v.z; s.w += v.w;
        }
        s4[sub * 64 + lane] = s;
        __syncthreads();
        if (t < 64) {
            float4 o = s4[t];
            #pragma unroll
            for (int p = 1; p < 8; ++p) {
                float4 v = s4[p * 64 + t];
                o.x += v.x; o.y += v.y; o.z += v.z; o.w += v.w;
            }
            *(float4*)(pgap + blk * 256 + 4 * t) = o;
        }
    }
    gridbar();

    // Prefetch this wave's phase-2 x tiles (L3-resident after phase 0) + wqkv rows.
    // Loads stay in flight / registers while phase 1 runs on 4 blocks.
    float4 px[2][4];
    #pragma unroll
    for (int j = 0; j < 2; ++j)
        #pragma unroll
        for (int bb = 0; bb < 4; ++bb)
            px[j][bb] = *(const float4*)(
                x + (size_t)(bb * 4096 + blk * 8 + sub + j * 2048) * 256 + 4 * lane);
    float4 wAv = *(const float4*)(wqkv + 12 * lane);
    float4 wBv = *(const float4*)(wqkv + 12 * lane + 4);
    float4 wCv = *(const float4*)(wqkv + 12 * lane + 8);

    // ============ Phase 1: middle stage (blocks 0..3, one per batch) ============
    if (blk < 4) {
        int b = blk;
        int c4 = lane * 4;            // col quad
        int rg = sub;                 // row group (wave-uniform)
        float* gn  = sB;
        float* sq  = sB + 256;
        float* sk  = sB + 512;
        float* sv  = sB + 768;
        float* att = sB + 1024;
        float* cm  = sB + 1280;
        float* Bc  = sB + 1536;
        float* swq = sB + 1792;       // 768
        float* red = sA;              // 6144

        if (t < 384) { swq[t] = wqkv[t]; swq[t + 384] = wqkv[t + 384]; }

        // A: gap reduce + CA BatchNorm
        {
            const float* pg = pgap + (size_t)(b * 64 + rg * 8) * 256 + c4;
            float4 s = make_float4(0.f, 0.f, 0.f, 0.f);
            #pragma unroll
            for (int u = 0; u < 8; ++u) {
                float4 v = *(const float4*)(pg + (size_t)u * 256);
                s.x += v.x; s.y += v.y; s.z += v.z; s.w += v.w;
            }
            *(float4*)(red + rg * 256 + c4) = s;
        }
        __syncthreads();
        if (t < 256) {
            float g = 0.f;
            #pragma unroll
            for (int r = 0; r < 8; ++r) g += red[r * 256 + t];
            g *= (1.0f / 4096.0f);
            float sc = cag[t] * rsqrtf(cav[t] + EPS);
            gn[t] = g * sc + (cab[t] - cam[t] * sc);
        }
        __syncthreads();

        // B: q/k/v = gn @ {wq,wk,wv} (weights L3-warm), float4 cols, 8-way row split
        {
            int rbase = rg * 32;
            float4 aq = make_float4(0.f, 0.f, 0.f, 0.f);
            float4 ak = aq, av = aq;
            const float* wqp = wq + (size_t)rbase * 256 + c4;
            const float* wkp = wk + (size_t)rbase * 256 + c4;
            const float* wvp = wv + (size_t)rbase * 256 + c4;
            #pragma unroll 8
            for (int i = 0; i < 32; ++i) {
                float g = gn[rbase + i];
                float4 w = *(const float4*)(wqp + (size_t)i * 256);
                aq.x = fmaf(g, w.x, aq.x); aq.y = fmaf(g, w.y, aq.y);
                aq.z = fmaf(g, w.z, aq.z); aq.w = fmaf(g, w.w, aq.w);
            }
            #pragma unroll 8
            for (int i = 0; i < 32; ++i) {
                float g = gn[rbase + i];
                float4 w = *(const float4*)(wkp + (size_t)i * 256);
                ak.x = fmaf(g, w.x, ak.x); ak.y = fmaf(g, w.y, ak.y);
                ak.z = fmaf(g, w.z, ak.z); ak.w = fmaf(g, w.w, ak.w);
            }
            #pragma unroll 8
            for (int i = 0; i < 32; ++i) {
                float g = gn[rbase + i];
                float4 w = *(const float4*)(wvp + (size_t)i * 256);
                av.x = fmaf(g, w.x, av.x); av.y = fmaf(g, w.y, av.y);
                av.z = fmaf(g, w.z, av.z); av.w = fmaf(g, w.w, av.w);
            }
            *(float4*)(red + (0 * 8 + rg) * 256 + c4) = aq;
            *(float4*)(red + (1 * 8 + rg) * 256 + c4) = ak;
            *(float4*)(red + (2 * 8 + rg) * 256 + c4) = av;
        }
        __syncthreads();
        {
            int m2 = t >> 8, c = t & 255;
            float s = 0.f;
            #pragma unroll
            for (int r = 0; r < 8; ++r) s += red[(m2 * 8 + r) * 256 + c];
            if (m2 == 0) sq[c] = s; else sk[c] = s;
            if (t < 256) {
                float s2 = 0.f;
                #pragma unroll
                for (int r = 0; r < 8; ++r) s2 += red[(16 + r) * 256 + t];
                sv[t] = s2;
            }
        }
        __syncthreads();

        // C: channel attention (rank-1 logits), j split over halves
        {
            int h = t >> 8, c = t & 255;
            float a = sq[c];
            int jb = h * 128;
            float mx = -1e30f;
            #pragma unroll 8
            for (int j = 0; j < 128; ++j) mx = fmaxf(mx, a * sk[jb + j]);
            float den = 0.f, num = 0.f;
            #pragma unroll 4
            for (int j = 0; j < 128; ++j) {
                float e = __expf(a * sk[jb + j] - mx);
                den += e; num = fmaf(e, sv[jb + j], num);
            }
            red[h * 256 + c] = mx;
            red[512 + h * 256 + c] = den;
            red[1024 + h * 256 + c] = num;
        }
        __syncthreads();
        if (t < 256) {
            float m0 = red[t], m1 = red[256 + t];
            float M = fmaxf(m0, m1);
            float s0 = __expf(m0 - M), s1 = __expf(m1 - M);
            float den = red[512 + t] * s0 + red[768 + t] * s1;
            float num = red[1024 + t] * s0 + red[1280 + t] * s1;
            att[t] = num / den;
        }
        __syncthreads();

        // D: cm = sigmoid(att @ wp)
        {
            int rbase = rg * 32;
            float4 ac = make_float4(0.f, 0.f, 0.f, 0.f);
            const float* wpp = wp + (size_t)rbase * 256 + c4;
            #pragma unroll 8
            for (int i = 0; i < 32; ++i) {
                float g = att[rbase + i];
                float4 w = *(const float4*)(wpp + (size_t)i * 256);
                ac.x = fmaf(g, w.x, ac.x); ac.y = fmaf(g, w.y, ac.y);
                ac.z = fmaf(g, w.z, ac.z); ac.w = fmaf(g, w.w, ac.w);
            }
            *(float4*)(red + rg * 256 + c4) = ac;
        }
        __syncthreads();
        if (t < 256) {
            float ac = 0.f;
            #pragma unroll
            for (int r = 0; r < 8; ++r) ac += red[r * 256 + t];
            cm[t] = 1.0f / (1.0f + __expf(-ac));
        }
        __syncthreads();

        // E: 10th percentile (linear): s[25] + 0.5*(s[26]-s[25])
        if (t < 256) {
            float my = cm[t];
            int rank = 0;
            for (int j = 0; j < 256; ++j) {
                float o = cm[j];
                rank += (o < my) ? 1 : ((o == my && j < t) ? 1 : 0);
            }
            if (rank == 25) sB[2560] = my;   // unique writers (ranks = permutation)
            if (rank == 26) sB[2561] = my;
        }
        __syncthreads();
        if (t == 0) sB[2562] = sB[2560] + 0.5f * (sB[2561] - sB[2560]);
        __syncthreads();

        // F: fold affine A,B; bias = B @ w_qkv
        if (t < 256) {
            float s2 = bng[t] * rsqrtf(bnv[t] + EPS);
            float o2 = bnb[t] - bnm[t] * s2;
            float cc = cm[t];
            float thr = sB[2562];
            float pm = (cc > thr) ? cc : 0.f;
            Aw[b * 256 + t] = (1.f + cc) * s2 * pm;
            Bc[t] = o2 * pm;
        }
        __syncthreads();
        if (t < 3) {
            float s3 = 0.f;
            for (int ch = 0; ch < 256; ++ch) s3 = fmaf(Bc[ch], swq[ch * 3 + t], s3);
            bias[b * 3 + t] = s3;
        }
    }
    gridbar();

    // ============ Phase 2: qkv = (x*A + B) @ w_qkv, wave per pixel ============
    {
        float w00 = wAv.x, w01 = wAv.y, w02 = wAv.z;
        float w10 = wAv.w, w11 = wBv.x, w12 = wBv.y;
        float w20 = wBv.z, w21 = wBv.w, w22 = wCv.x;
        float w30 = wCv.y, w31 = wCv.z, w32 = wCv.w;
        int wid = blk * 8 + sub;          // 0..2047
        #pragma unroll
        for (int bb = 0; bb < 4; ++bb) {
            float4 A4 = *(const float4*)(Aw + bb * 256 + 4 * lane);
            float bq = bias[bb * 3 + 0];  // uniform addr -> broadcast load
            float bk = bias[bb * 3 + 1];
            float bv = bias[bb * 3 + 2];
            #pragma unroll
            for (int j = 0; j < 2; ++j) {
                int pix = bb * 4096 + wid + j * 2048;
                float4 xv = px[j][bb];
                float t0 = xv.x * A4.x, t1 = xv.y * A4.y;
                float t2 = xv.z * A4.z, t3 = xv.w * A4.w;
                float q = t0 * w00 + t1 * w10 + t2 * w20 + t3 * w30;
                float k = t0 * w01 + t1 * w11 + t2 * w21 + t3 * w31;
                float v = t0 * w02 + t1 * w12 + t2 * w22 + t3 * w32;
                #pragma unroll
                for (int m2 = 1; m2 < 64; m2 <<= 1) {
                    q += __shfl_xor(q, m2, 64);
                    k += __shfl_xor(k, m2, 64);
                    v += __shfl_xor(v, m2, 64);
                }
                if (lane == 0) {
                    qs[pix] = q + bq; ks[pix] = k + bk; vs[pix] = v + bv;
                }
            }
        }
    }
    gridbar();

    // ============ Phase 3: spatial attention + output ============
    {
        float* pden = sA;            // [8][64]
        float* pnum = sA + 512;
        float* rmax = sB;
        float* rmin = sB + 8;
        int b = blk >> 6, ic = blk & 63;
        int base = b * 4096;
        const float4* k4 = (const float4*)(ks + base);
        const float4* v4 = (const float4*)(vs + base);
        float kmx = -1e30f, kmn = 1e30f;
        #pragma unroll
        for (int u = 0; u < 2; ++u) {
            int i = t + u * 512;          // 0..1023 float4 rows
            float4 kk = k4[i], vv = v4[i];
            s4[i * 2]     = make_float4(kk.x, vv.x, kk.y, vv.y);
            s4[i * 2 + 1] = make_float4(kk.z, vv.z, kk.w, vv.w);
            kmx = fmaxf(kmx, fmaxf(fmaxf(kk.x, kk.y), fmaxf(kk.z, kk.w)));
            kmn = fminf(kmn, fminf(fminf(kk.x, kk.y), fminf(kk.z, kk.w)));
        }
        #pragma unroll
        for (int m2 = 1; m2 < 64; m2 <<= 1) {
            kmx = fmaxf(kmx, __shfl_xor(kmx, m2, 64));
            kmn = fminf(kmn, __shfl_xor(kmn, m2, 64));
        }
        if (lane == 0) { rmax[sub] = kmx; rmin[sub] = kmn; }
        __syncthreads();
        float mx = rmax[0], mn = rmin[0];
        #pragma unroll
        for (int s = 1; s < 8; ++s) { mx = fmaxf(mx, rmax[s]); mn = fminf(mn, rmin[s]); }

        int row = ic * 64 + lane;
        float a = qs[base + row];
        float m = (a >= 0.f) ? a * mx : a * mn;   // exact global row max (rank-1)
        float den0 = 0.f, num0 = 0.f, den1 = 0.f, num1 = 0.f;
        const float4* sp = s4 + sub * 256;        // this wave's 512-j slice
        #pragma unroll 4
        for (int j = 0; j < 256; ++j) {
            float4 kv = sp[j];                    // uniform addr -> broadcast
            float e0 = __expf(fmaf(a, kv.x, -m));
            float e1 = __expf(fmaf(a, kv.z, -m));
            den0 += e0; num0 = fmaf(e0, kv.y, num0);
            den1 += e1; num1 = fmaf(e1, kv.w, num1);
        }
        pden[sub * 64 + lane] = den0 + den1;
        pnum[sub * 64 + lane] = num0 + num1;
        __syncthreads();
        if (t < 64) {
            float den = 0.f, num = 0.f;
            #pragma unroll
            for (int s = 0; s < 8; ++s) { den += pden[s * 64 + t]; num += pnum[s * 64 + t]; }
            int r = ic * 64 + t;
            float vrow = (r & 1) ? s4[r >> 1].w : s4[r >> 1].y;
            out[base + r] = vrow + num / den;
        }
    }
}

extern "C" void kernel_launch(void* const* d_in, const int* in_sizes, int n_in,
                              void* d_out, int out_size, void* d_ws, size_t ws_size,
                              hipStream_t stream) {
    const float* x    = (const float*)d_in[0];
    const float* cag  = (const float*)d_in[1];
    const float* cab  = (const float*)d_in[2];
    const float* cam  = (const float*)d_in[3];
    const float* cav  = (const float*)d_in[4];
    const float* wq   = (const float*)d_in[5];
    const float* wk   = (const float*)d_in[6];
    const float* wv   = (const float*)d_in[7];
    const float* wp   = (const float*)d_in[8];
    const float* bng  = (const float*)d_in[9];
    const float* bnb  = (const float*)d_in[10];
    const float* bnm  = (const float*)d_in[11];
    const float* bnv  = (const float*)d_in[12];
    const float* wqkv = (const float*)d_in[13];

    float* ws = (float*)d_ws;
    mega<<<dim3(256), dim3(512), 0, stream>>>(x, cag, cab, cam, cav,
                                              wq, wk, wv, wp,
                                              bng, bnb, bnm, bnv, wqkv,
                                              ws, (float*)d_out);
}

// Round 3
// 276.728 us; speedup vs baseline: 1.0087x; 1.0087x over previous
//
#include <hip/hip_runtime.h>

#define EPS 1e-3f
#define NBLK 256

// ---- ws layout (float offsets) ----
#define OFF_PGAP   0         // 65536  : per-(block,channel) gap partial sums [256][256]
#define OFF_A      65536     // 1024   : per-channel affine scale A[b][c]
#define OFF_BIAS   66560     // 16     : folded qkv bias [4][3]
#define OFF_QS     66576     // 16384  : spatial q  [4][4096]
#define OFF_KS     82960     // 16384  : spatial k
#define OFF_VS     99344     // 16384  : spatial v

// ---- contention-free grid barrier state (module .data, zero-init, monotonic) ----
// Each block owns a padded flag line (no RMW, no false sharing). Block 0 detects
// all-arrived (256 threads each poll ONE flag) and publishes g_release; other
// blocks spin read-only on g_release (single line, written once per barrier).
// Epochs are monotonic across launches/replays: base = g_release at kernel entry.
__device__ unsigned g_flags[NBLK * 32];   // 128B stride per block
__device__ unsigned g_release;

__device__ __forceinline__ void gridbar(unsigned epoch) {
    __syncthreads();            // per-wave vmcnt(0) drain: block's stores are in L2
    int t = threadIdx.x;
    int blk = blockIdx.x;
    if (blk == 0) {
        if (t == 0) {
            __threadfence();    // wbl2: make block-0 data device-visible
            __hip_atomic_store(&g_flags[0], epoch, __ATOMIC_RELEASE,
                               __HIP_MEMORY_SCOPE_AGENT);
        }
        if (t < NBLK) {
            unsigned tries = 0;
            while (__hip_atomic_load(&g_flags[t * 32], __ATOMIC_RELAXED,
                                     __HIP_MEMORY_SCOPE_AGENT) < epoch) {
                __builtin_amdgcn_s_sleep(2);
                if (++tries > 10000000u) break;    // hang safety valve
            }
        }
        __syncthreads();        // all flags seen
        if (t == 0) {
            __hip_atomic_store(&g_release, epoch, __ATOMIC_RELEASE,
                               __HIP_MEMORY_SCOPE_AGENT);
            __threadfence();    // inv: fresh reads for block 0's own waves
        }
        __syncthreads();
    } else {
        if (t == 0) {
            __threadfence();    // wbl2: make this block's data device-visible
            __hip_atomic_store(&g_flags[blk * 32], epoch, __ATOMIC_RELEASE,
                               __HIP_MEMORY_SCOPE_AGENT);
            unsigned tries = 0;
            while (__hip_atomic_load(&g_release, __ATOMIC_ACQUIRE,
                                     __HIP_MEMORY_SCOPE_AGENT) < epoch) {
                __builtin_amdgcn_s_sleep(2);
                if (++tries > 10000000u) break;    // hang safety valve
            }
            __threadfence();    // inv L1/L2 before block reads others' data
        }
        __syncthreads();
    }
}

// One persistent kernel, 256 blocks (1/CU, all co-resident) x 512 threads.
// Phase 0: gap partials + weight L3-warm
// Phase 1: full middle stage on 4 blocks (others hold phase-2 x prefetch in regs)
// Phase 2: qkv = (x*A + B) @ w_qkv, wave-per-pixel
// Phase 3: spatial attention + output
__global__ __launch_bounds__(512) void mega(
    const float* __restrict__ x,
    const float* __restrict__ cag, const float* __restrict__ cab,
    const float* __restrict__ cam, const float* __restrict__ cav,
    const float* __restrict__ wq, const float* __restrict__ wk,
    const float* __restrict__ wv, const float* __restrict__ wp,
    const float* __restrict__ bng, const float* __restrict__ bnb,
    const float* __restrict__ bnm, const float* __restrict__ bnv,
    const float* __restrict__ wqkv,
    float* __restrict__ ws, float* __restrict__ out)
{
    __shared__ float4 s4[2048];   // 32KB: phase0 gap partials(512) / phase3 skv(2048)
    __shared__ float  sA[6144];   // 24KB: phase1 matmul partials / phase3 pden+pnum
    __shared__ float  sB[2576];   // 10KB: phase1 vectors+swqkv / phase3 rmax,rmin
    __shared__ unsigned sBase;

    float* pgap = ws + OFF_PGAP;
    float* Aw   = ws + OFF_A;
    float* bias = ws + OFF_BIAS;
    float* qs   = ws + OFF_QS;
    float* ks   = ws + OFF_KS;
    float* vs   = ws + OFF_VS;

    int blk = blockIdx.x;             // 0..255
    int t = threadIdx.x;              // 0..511
    int lane = t & 63, sub = t >> 6;  // sub = wave id (wave-uniform)

    if (t == 0)
        sBase = __hip_atomic_load(&g_release, __ATOMIC_RELAXED,
                                  __HIP_MEMORY_SCOPE_AGENT);

    // ============ Phase 0: gap partials (+ L3 warm of phase-1 operands) ============
    {
        if (t < 256) {   // 4KB weight slice per block -> all of wq/wk/wv/wp into L3
            const float* wmat = (blk < 64) ? wq : (blk < 128) ? wk
                              : (blk < 192) ? wv : wp;
            float4 w4 = *(const float4*)(wmat + (size_t)(blk & 63) * 1024 + 4 * t);
            asm volatile("" :: "v"(w4.x), "v"(w4.y), "v"(w4.z), "v"(w4.w));
        }
        if (blk == 1 && t < 256) {
            float z = bng[t] + bnb[t] + bnm[t] + bnv[t];
            asm volatile("" :: "v"(z));
        }
        if (blk == 2 && t < 256) {
            float z = cag[t] + cab[t] + cam[t] + cav[t];
            asm volatile("" :: "v"(z));
        }
        // 64 pixels per block: 8 waves x 8 pixels, float4 channel quads
        const float* xp = x + ((size_t)blk * 64 + sub * 8) * 256 + 4 * lane;
        float4 s = make_float4(0.f, 0.f, 0.f, 0.f);
        #pragma unroll
        for (int u = 0; u < 8; ++u) {
            float4 v = *(const float4*)(xp + (size_t)u * 256);
            s.x += v.x; s.y += v.y; s.z += v.z; s.w += v.w;
        }
        s4[sub * 64 + lane] = s;
        __syncthreads();              // also publishes sBase
        if (t < 64) {
            float4 o = s4[t];
            #pragma unroll
            for (int p = 1; p < 8; ++p) {
                float4 v = s4[p * 64 + t];
                o.x += v.x; o.y += v.y; o.z += v.z; o.w += v.w;
            }
            *(float4*)(pgap + blk * 256 + 4 * t) = o;
        }
    }
    unsigned base = sBase;
    gridbar(base + 1);

    // Prefetch this wave's phase-2 x tiles (L3-resident after phase 0) + wqkv rows.
    // Loads stay in flight / registers while phase 1 runs on 4 blocks.
    float4 px[2][4];
    #pragma unroll
    for (int j = 0; j < 2; ++j)
        #pragma unroll
        for (int bb = 0; bb < 4; ++bb)
            px[j][bb] = *(const float4*)(
                x + (size_t)(bb * 4096 + blk * 8 + sub + j * 2048) * 256 + 4 * lane);
    float4 wAv = *(const float4*)(wqkv + 12 * lane);
    float4 wBv = *(const float4*)(wqkv + 12 * lane + 4);
    float4 wCv = *(const float4*)(wqkv + 12 * lane + 8);

    // ============ Phase 1: middle stage (blocks 0..3, one per batch) ============
    if (blk < 4) {
        int b = blk;
        int c4 = lane * 4;            // col quad
        int rg = sub;                 // row group (wave-uniform)
        float* gn  = sB;
        float* sq  = sB + 256;
        float* sk  = sB + 512;
        float* sv  = sB + 768;
        float* att = sB + 1024;
        float* cm  = sB + 1280;
        float* Bc  = sB + 1536;
        float* swq = sB + 1792;       // 768
        float* red = sA;              // 6144

        if (t < 384) { swq[t] = wqkv[t]; swq[t + 384] = wqkv[t + 384]; }

        // A: gap reduce + CA BatchNorm
        {
            const float* pg = pgap + (size_t)(b * 64 + rg * 8) * 256 + c4;
            float4 s = make_float4(0.f, 0.f, 0.f, 0.f);
            #pragma unroll
            for (int u = 0; u < 8; ++u) {
                float4 v = *(const float4*)(pg + (size_t)u * 256);
                s.x += v.x; s.y += v.y; s.z += v.z; s.w += v.w;
            }
            *(float4*)(red + rg * 256 + c4) = s;
        }
        __syncthreads();
        if (t < 256) {
            float g = 0.f;
            #pragma unroll
            for (int r = 0; r < 8; ++r) g += red[r * 256 + t];
            g *= (1.0f / 4096.0f);
            float sc = cag[t] * rsqrtf(cav[t] + EPS);
            gn[t] = g * sc + (cab[t] - cam[t] * sc);
        }
        __syncthreads();

        // B: q/k/v = gn @ {wq,wk,wv} (weights L3-warm), float4 cols, 8-way row split
        {
            int rbase = rg * 32;
            float4 aq = make_float4(0.f, 0.f, 0.f, 0.f);
            float4 ak = aq, av = aq;
            const float* wqp = wq + (size_t)rbase * 256 + c4;
            const float* wkp = wk + (size_t)rbase * 256 + c4;
            const float* wvp = wv + (size_t)rbase * 256 + c4;
            #pragma unroll 8
            for (int i = 0; i < 32; ++i) {
                float g = gn[rbase + i];
                float4 w = *(const float4*)(wqp + (size_t)i * 256);
                aq.x = fmaf(g, w.x, aq.x); aq.y = fmaf(g, w.y, aq.y);
                aq.z = fmaf(g, w.z, aq.z); aq.w = fmaf(g, w.w, aq.w);
            }
            #pragma unroll 8
            for (int i = 0; i < 32; ++i) {
                float g = gn[rbase + i];
                float4 w = *(const float4*)(wkp + (size_t)i * 256);
                ak.x = fmaf(g, w.x, ak.x); ak.y = fmaf(g, w.y, ak.y);
                ak.z = fmaf(g, w.z, ak.z); ak.w = fmaf(g, w.w, ak.w);
            }
            #pragma unroll 8
            for (int i = 0; i < 32; ++i) {
                float g = gn[rbase + i];
                float4 w = *(const float4*)(wvp + (size_t)i * 256);
                av.x = fmaf(g, w.x, av.x); av.y = fmaf(g, w.y, av.y);
                av.z = fmaf(g, w.z, av.z); av.w = fmaf(g, w.w, av.w);
            }
            *(float4*)(red + (0 * 8 + rg) * 256 + c4) = aq;
            *(float4*)(red + (1 * 8 + rg) * 256 + c4) = ak;
            *(float4*)(red + (2 * 8 + rg) * 256 + c4) = av;
        }
        __syncthreads();
        {
            int m2 = t >> 8, c = t & 255;
            float s = 0.f;
            #pragma unroll
            for (int r = 0; r < 8; ++r) s += red[(m2 * 8 + r) * 256 + c];
            if (m2 == 0) sq[c] = s; else sk[c] = s;
            if (t < 256) {
                float s2 = 0.f;
                #pragma unroll
                for (int r = 0; r < 8; ++r) s2 += red[(16 + r) * 256 + t];
                sv[t] = s2;
            }
        }
        __syncthreads();

        // C: channel attention (rank-1 logits), j split over halves
        {
            int h = t >> 8, c = t & 255;
            float a = sq[c];
            int jb = h * 128;
            float mx = -1e30f;
            #pragma unroll 8
            for (int j = 0; j < 128; ++j) mx = fmaxf(mx, a * sk[jb + j]);
            float den = 0.f, num = 0.f;
            #pragma unroll 4
            for (int j = 0; j < 128; ++j) {
                float e = __expf(a * sk[jb + j] - mx);
                den += e; num = fmaf(e, sv[jb + j], num);
            }
            red[h * 256 + c] = mx;
            red[512 + h * 256 + c] = den;
            red[1024 + h * 256 + c] = num;
        }
        __syncthreads();
        if (t < 256) {
            float m0 = red[t], m1 = red[256 + t];
            float M = fmaxf(m0, m1);
            float s0 = __expf(m0 - M), s1 = __expf(m1 - M);
            float den = red[512 + t] * s0 + red[768 + t] * s1;
            float num = red[1024 + t] * s0 + red[1280 + t] * s1;
            att[t] = num / den;
        }
        __syncthreads();

        // D: cm = sigmoid(att @ wp)
        {
            int rbase = rg * 32;
            float4 ac = make_float4(0.f, 0.f, 0.f, 0.f);
            const float* wpp = wp + (size_t)rbase * 256 + c4;
            #pragma unroll 8
            for (int i = 0; i < 32; ++i) {
                float g = att[rbase + i];
                float4 w = *(const float4*)(wpp + (size_t)i * 256);
                ac.x = fmaf(g, w.x, ac.x); ac.y = fmaf(g, w.y, ac.y);
                ac.z = fmaf(g, w.z, ac.z); ac.w = fmaf(g, w.w, ac.w);
            }
            *(float4*)(red + rg * 256 + c4) = ac;
        }
        __syncthreads();
        if (t < 256) {
            float ac = 0.f;
            #pragma unroll
            for (int r = 0; r < 8; ++r) ac += red[r * 256 + t];
            cm[t] = 1.0f / (1.0f + __expf(-ac));
        }
        __syncthreads();

        // E: 10th percentile (linear): s[25] + 0.5*(s[26]-s[25])
        if (t < 256) {
            float my = cm[t];
            int rank = 0;
            for (int j = 0; j < 256; ++j) {
                float o = cm[j];
                rank += (o < my) ? 1 : ((o == my && j < t) ? 1 : 0);
            }
            if (rank == 25) sB[2560] = my;   // unique writers (ranks = permutation)
            if (rank == 26) sB[2561] = my;
        }
        __syncthreads();
        if (t == 0) sB[2562] = sB[2560] + 0.5f * (sB[2561] - sB[2560]);
        __syncthreads();

        // F: fold affine A,B; bias = B @ w_qkv
        if (t < 256) {
            float s2 = bng[t] * rsqrtf(bnv[t] + EPS);
            float o2 = bnb[t] - bnm[t] * s2;
            float cc = cm[t];
            float thr = sB[2562];
            float pm = (cc > thr) ? cc : 0.f;
            Aw[b * 256 + t] = (1.f + cc) * s2 * pm;
            Bc[t] = o2 * pm;
        }
        __syncthreads();
        if (t < 3) {
            float s3 = 0.f;
            for (int ch = 0; ch < 256; ++ch) s3 = fmaf(Bc[ch], swq[ch * 3 + t], s3);
            bias[b * 3 + t] = s3;
        }
    }
    gridbar(base + 2);

    // ============ Phase 2: qkv = (x*A + B) @ w_qkv, wave per pixel ============
    {
        float w00 = wAv.x, w01 = wAv.y, w02 = wAv.z;
        float w10 = wAv.w, w11 = wBv.x, w12 = wBv.y;
        float w20 = wBv.z, w21 = wBv.w, w22 = wCv.x;
        float w30 = wCv.y, w31 = wCv.z, w32 = wCv.w;
        int wid = blk * 8 + sub;          // 0..2047
        #pragma unroll
        for (int bb = 0; bb < 4; ++bb) {
            float4 A4 = *(const float4*)(Aw + bb * 256 + 4 * lane);
            float bq = bias[bb * 3 + 0];  // uniform addr -> broadcast load
            float bk = bias[bb * 3 + 1];
            float bv = bias[bb * 3 + 2];
            #pragma unroll
            for (int j = 0; j < 2; ++j) {
                int pix = bb * 4096 + wid + j * 2048;
                float4 xv = px[j][bb];
                float t0 = xv.x * A4.x, t1 = xv.y * A4.y;
                float t2 = xv.z * A4.z, t3 = xv.w * A4.w;
                float q = t0 * w00 + t1 * w10 + t2 * w20 + t3 * w30;
                float k = t0 * w01 + t1 * w11 + t2 * w21 + t3 * w31;
                float v = t0 * w02 + t1 * w12 + t2 * w22 + t3 * w32;
                #pragma unroll
                for (int m2 = 1; m2 < 64; m2 <<= 1) {
                    q += __shfl_xor(q, m2, 64);
                    k += __shfl_xor(k, m2, 64);
                    v += __shfl_xor(v, m2, 64);
                }
                if (lane == 0) {
                    qs[pix] = q + bq; ks[pix] = k + bk; vs[pix] = v + bv;
                }
            }
        }
    }
    gridbar(base + 3);

    // ============ Phase 3: spatial attention + output ============
    {
        float* pden = sA;            // [8][64]
        float* pnum = sA + 512;
        float* rmax = sB;
        float* rmin = sB + 8;
        int b = blk >> 6, ic = blk & 63;
        int base3 = b * 4096;
        const float4* k4 = (const float4*)(ks + base3);
        const float4* v4 = (const float4*)(vs + base3);
        float kmx = -1e30f, kmn = 1e30f;
        #pragma unroll
        for (int u = 0; u < 2; ++u) {
            int i = t + u * 512;          // 0..1023 float4 rows
            float4 kk = k4[i], vv = v4[i];
            s4[i * 2]     = make_float4(kk.x, vv.x, kk.y, vv.y);
            s4[i * 2 + 1] = make_float4(kk.z, vv.z, kk.w, vv.w);
            kmx = fmaxf(kmx, fmaxf(fmaxf(kk.x, kk.y), fmaxf(kk.z, kk.w)));
            kmn = fminf(kmn, fminf(fminf(kk.x, kk.y), fminf(kk.z, kk.w)));
        }
        #pragma unroll
        for (int m2 = 1; m2 < 64; m2 <<= 1) {
            kmx = fmaxf(kmx, __shfl_xor(kmx, m2, 64));
            kmn = fminf(kmn, __shfl_xor(kmn, m2, 64));
        }
        if (lane == 0) { rmax[sub] = kmx; rmin[sub] = kmn; }
        __syncthreads();
        float mx = rmax[0], mn = rmin[0];
        #pragma unroll
        for (int s = 1; s < 8; ++s) { mx = fmaxf(mx, rmax[s]); mn = fminf(mn, rmin[s]); }

        int row = ic * 64 + lane;
        float a = qs[base3 + row];
        float m = (a >= 0.f) ? a * mx : a * mn;   // exact global row max (rank-1)
        float den0 = 0.f, num0 = 0.f, den1 = 0.f, num1 = 0.f;
        const float4* sp = s4 + sub * 256;        // this wave's 512-j slice
        #pragma unroll 4
        for (int j = 0; j < 256; ++j) {
            float4 kv = sp[j];                    // uniform addr -> broadcast
            float e0 = __expf(fmaf(a, kv.x, -m));
            float e1 = __expf(fmaf(a, kv.z, -m));
            den0 += e0; num0 = fmaf(e0, kv.y, num0);
            den1 += e1; num1 = fmaf(e1, kv.w, num1);
        }
        pden[sub * 64 + lane] = den0 + den1;
        pnum[sub * 64 + lane] = num0 + num1;
        __syncthreads();
        if (t < 64) {
            float den = 0.f, num = 0.f;
            #pragma unroll
            for (int s = 0; s < 8; ++s) { den += pden[s * 64 + t]; num += pnum[s * 64 + t]; }
            int r = ic * 64 + t;
            float vrow = (r & 1) ? s4[r >> 1].w : s4[r >> 1].y;
            out[base3 + r] = vrow + num / den;
        }
    }
}

extern "C" void kernel_launch(void* const* d_in, const int* in_sizes, int n_in,
                              void* d_out, int out_size, void* d_ws, size_t ws_size,
                              hipStream_t stream) {
    const float* x    = (const float*)d_in[0];
    const float* cag  = (const float*)d_in[1];
    const float* cab  = (const float*)d_in[2];
    const float* cam  = (const float*)d_in[3];
    const float* cav  = (const float*)d_in[4];
    const float* wq   = (const float*)d_in[5];
    const float* wk   = (const float*)d_in[6];
    const float* wv   = (const float*)d_in[7];
    const float* wp   = (const float*)d_in[8];
    const float* bng  = (const float*)d_in[9];
    const float* bnb  = (const float*)d_in[10];
    const float* bnm  = (const float*)d_in[11];
    const float* bnv  = (const float*)d_in[12];
    const float* wqkv = (const float*)d_in[13];

    float* ws = (float*)d_ws;
    mega<<<dim3(256), dim3(512), 0, stream>>>(x, cag, cab, cam, cav,
                                              wq, wk, wv, wp,
                                              bng, bnb, bnm, bnv, wqkv,
                                              ws, (float*)d_out);
}

// Round 4
// 164.571 us; speedup vs baseline: 1.6961x; 1.6815x over previous
//
#include <hip/hip_runtime.h>

#define EPS 1e-3f
#define NBLK 256

// ---- ws layout (float offsets; 1KB guard gaps between regions) ----
#define OFF_PGAP   0         // 65536  : gap partials [256 blk][256 ch]
#define OFF_PART   66560     // 98304  : qkv split-K partials [3][32][4][256]
#define OFF_QS     165888    // 16384  : spatial q [4][4096]
#define OFF_KS     182528    // 16384  : spatial k
#define OFF_VS     199168    // 16384  : spatial v

// ---- agent-scope (L3-coherent, L2-bypass) helpers: NO cache-maintenance ops ----
__device__ __forceinline__ void st_wt(float* p, float v) {
    __hip_atomic_store(p, v, __ATOMIC_RELAXED, __HIP_MEMORY_SCOPE_AGENT);
}
__device__ __forceinline__ void st_wt2(float* p, float a, float b) {
    union { float f[2]; unsigned long long u; } x; x.f[0] = a; x.f[1] = b;
    __hip_atomic_store((unsigned long long*)p, x.u, __ATOMIC_RELAXED,
                       __HIP_MEMORY_SCOPE_AGENT);
}
__device__ __forceinline__ float ld_wt(const float* p) {
    return __hip_atomic_load(p, __ATOMIC_RELAXED, __HIP_MEMORY_SCOPE_AGENT);
}
__device__ __forceinline__ float2 ld_wt2(const float* p) {
    union { unsigned long long u; float f[2]; } x;
    x.u = __hip_atomic_load((const unsigned long long*)p, __ATOMIC_RELAXED,
                            __HIP_MEMORY_SCOPE_AGENT);
    return make_float2(x.f[0], x.f[1]);
}

// ---- pure flag-array grid barrier: zero fences, zero invalidates ----
// Visibility contract: all cross-block traffic uses the agent-scope WT helpers
// above, so data is at the coherence point (L3) as soon as vmcnt drains —
// which __syncthreads() (pre-barrier) and the release flag store guarantee.
__device__ unsigned g_flags[NBLK * 32];   // 128B stride, one line per block
__device__ unsigned g_release;

__device__ __forceinline__ void gridbar(unsigned epoch) {
    __syncthreads();                 // drains every wave's vmcnt (WT stores at L3)
    int t = threadIdx.x, blk = blockIdx.x;
    if (blk == 0) {
        if (t == 0)
            __hip_atomic_store(&g_flags[0], epoch, __ATOMIC_RELEASE,
                               __HIP_MEMORY_SCOPE_AGENT);
        if (t > 0 && t < NBLK) {
            unsigned tries = 0;
            while (__hip_atomic_load(&g_flags[t * 32], __ATOMIC_RELAXED,
                                     __HIP_MEMORY_SCOPE_AGENT) < epoch) {
                __builtin_amdgcn_s_sleep(1);
                if (++tries > 8000000u) break;     // hang safety valve
            }
        }
        __syncthreads();
        if (t == 0)
            __hip_atomic_store(&g_release, epoch, __ATOMIC_RELEASE,
                               __HIP_MEMORY_SCOPE_AGENT);
        __syncthreads();
    } else {
        if (t == 0) {
            __hip_atomic_store(&g_flags[blk * 32], epoch, __ATOMIC_RELEASE,
                               __HIP_MEMORY_SCOPE_AGENT);
            unsigned tries = 0;
            while (__hip_atomic_load(&g_release, __ATOMIC_RELAXED,
                                     __HIP_MEMORY_SCOPE_AGENT) < epoch) {
                __builtin_amdgcn_s_sleep(1);
                if (++tries > 8000000u) break;     // hang safety valve
            }
        }
        __syncthreads();
    }
}

// Persistent kernel, 256 blocks x 512 threads, 3 grid barriers.
// P0 : gap partials (all blocks) + weight L3 warm            -> pgap (WT)
// P1a: split-K qkv matmul, 96 blocks (3 mats x 32 rowgroups) -> part (WT)
// P1b: EVERY block redundantly: reduce partials, channel softmax (exact rank-1
//      max), wp matmul, sigmoid, percentile, fold A/bias  -> LDS only (no bar!)
// P2 : qkv = (x*A + B) @ w_qkv, wave per pixel               -> qs/ks/vs (WT)
// P3 : spatial attention + output
__global__ __launch_bounds__(512) void mega(
    const float* __restrict__ x,
    const float* __restrict__ cag, const float* __restrict__ cab,
    const float* __restrict__ cam, const float* __restrict__ cav,
    const float* __restrict__ wq, const float* __restrict__ wk,
    const float* __restrict__ wv, const float* __restrict__ wp,
    const float* __restrict__ bng, const float* __restrict__ bnb,
    const float* __restrict__ bnm, const float* __restrict__ bnv,
    const float* __restrict__ wqkv,
    float* __restrict__ ws, float* __restrict__ out)
{
    __shared__ float4 s4[2048];   // 32KB: P0 partials / P1b wp-red / P3 skv
    __shared__ float  sA[6144];   // 24KB: P1a red / P1b sq,sk,sv,att,cm,Aw / P3 pden,pnum
    __shared__ float  sB[2576];   // 10KB: P1a gpart,gn / P1b Bc,swq,scalars / P3 rmax,rmin
    __shared__ unsigned sBase;

    float* pgap = ws + OFF_PGAP;
    float* part = ws + OFF_PART;
    float* qs   = ws + OFF_QS;
    float* ks   = ws + OFF_KS;
    float* vs   = ws + OFF_VS;

    int blk = blockIdx.x;             // 0..255
    int t = threadIdx.x;              // 0..511
    int lane = t & 63, sub = t >> 6;  // sub = wave id (wave-uniform)

    if (t == 0)
        sBase = __hip_atomic_load(&g_release, __ATOMIC_RELAXED,
                                  __HIP_MEMORY_SCOPE_AGENT);

    // ================= P0: gap partials + L3 warm =================
    {
        if (t < 256) {   // 4KB weight slice per block -> wq/wk/wv/wp into L3
            const float* wmat = (blk < 64) ? wq : (blk < 128) ? wk
                              : (blk < 192) ? wv : wp;
            float4 w4 = *(const float4*)(wmat + (size_t)(blk & 63) * 1024 + 4 * t);
            asm volatile("" :: "v"(w4.x), "v"(w4.y), "v"(w4.z), "v"(w4.w));
        }
        if (blk == 1 && t < 256) {
            float z = bng[t] + bnb[t] + bnm[t] + bnv[t];
            asm volatile("" :: "v"(z));
        }
        if (blk == 2 && t < 256) {
            float z = cag[t] + cab[t] + cam[t] + cav[t];
            asm volatile("" :: "v"(z));
        }
        const float* xp = x + ((size_t)blk * 64 + sub * 8) * 256 + 4 * lane;
        float4 s = make_float4(0.f, 0.f, 0.f, 0.f);
        #pragma unroll
        for (int u = 0; u < 8; ++u) {
            float4 v = *(const float4*)(xp + (size_t)u * 256);
            s.x += v.x; s.y += v.y; s.z += v.z; s.w += v.w;
        }
        s4[sub * 64 + lane] = s;
        __syncthreads();              // also publishes sBase
        if (t < 64) {
            float4 o = s4[t];
            #pragma unroll
            for (int p = 1; p < 8; ++p) {
                float4 v = s4[p * 64 + t];
                o.x += v.x; o.y += v.y; o.z += v.z; o.w += v.w;
            }
            st_wt2(pgap + blk * 256 + 4 * t,     o.x, o.y);
            st_wt2(pgap + blk * 256 + 4 * t + 2, o.z, o.w);
        }
    }
    unsigned base = sBase;
    gridbar(base + 1);

    // Prefetch this wave's P2 x tiles (L3-resident after P0) + wqkv rows.
    float4 px[2][4];
    #pragma unroll
    for (int j = 0; j < 2; ++j)
        #pragma unroll
        for (int bb = 0; bb < 4; ++bb)
            px[j][bb] = *(const float4*)(
                x + (size_t)(bb * 4096 + blk * 8 + sub + j * 2048) * 256 + 4 * lane);
    float4 wAv = *(const float4*)(wqkv + 12 * lane);
    float4 wBv = *(const float4*)(wqkv + 12 * lane + 4);
    float4 wCv = *(const float4*)(wqkv + 12 * lane + 8);

    // ================= P1a: split-K qkv matmul (96 blocks) =================
    if (blk < 96) {
        int m = blk / 32, g = blk % 32;       // matrix, rowgroup
        int r0 = g * 8;
        const float* W = (m == 0) ? wq : (m == 1) ? wk : wv;
        float* gpart = sB;                    // [4][8][16]
        float* gn_s  = sB + 512;              // [4][8]

        {   // gn for rows r0..r0+7, 4 batches: 512 workers = (b, row, p4)
            int b = t >> 7, row = (t >> 4) & 7, p4 = t & 15;
            float s = 0.f;
            #pragma unroll
            for (int q = 0; q < 4; ++q)
                s += ld_wt(pgap + (size_t)(b * 64 + p4 * 4 + q) * 256 + r0 + row);
            gpart[b * 128 + row * 16 + p4] = s;
        }
        __syncthreads();
        if (t < 32) {
            int b = t >> 3, row = t & 7;
            float s = 0.f;
            #pragma unroll
            for (int p = 0; p < 16; ++p) s += gpart[b * 128 + row * 16 + p];
            float gv = s * (1.0f / 4096.0f);
            int c = r0 + row;
            float sc = cag[c] * rsqrtf(cav[c] + EPS);
            gn_s[b * 8 + row] = gv * sc + (cab[c] - cam[c] * sc);
        }
        __syncthreads();
        {   // rows split h=t>>8 (4 rows each), col c=t&255, coalesced W loads
            int c = t & 255, h = t >> 8;
            float a0 = 0.f, a1 = 0.f, a2 = 0.f, a3 = 0.f;
            #pragma unroll
            for (int rr = 0; rr < 4; ++rr) {
                int ri = h * 4 + rr;
                float w = W[(size_t)(r0 + ri) * 256 + c];
                a0 = fmaf(gn_s[0 * 8 + ri], w, a0);
                a1 = fmaf(gn_s[1 * 8 + ri], w, a1);
                a2 = fmaf(gn_s[2 * 8 + ri], w, a2);
                a3 = fmaf(gn_s[3 * 8 + ri], w, a3);
            }
            sA[(h * 4 + 0) * 256 + c] = a0;
            sA[(h * 4 + 1) * 256 + c] = a1;
            sA[(h * 4 + 2) * 256 + c] = a2;
            sA[(h * 4 + 3) * 256 + c] = a3;
        }
        __syncthreads();
        {   // combine halves, WT-store partials [m][g][b][c]
            int b = t >> 7, c0 = (t & 127) * 2;
            float v0 = sA[b * 256 + c0]     + sA[(4 + b) * 256 + c0];
            float v1 = sA[b * 256 + c0 + 1] + sA[(4 + b) * 256 + c0 + 1];
            st_wt2(part + (size_t)((m * 32 + g) * 4 + b) * 256 + c0, v0, v1);
        }
    }
    gridbar(base + 2);

    // ====== P1b: redundant tail on EVERY block (LDS-local, no barrier) ======
    {
        float* sq  = sA;                // [4][256]
        float* sk  = sA + 1024;
        float* sv  = sA + 2048;
        float* att = sA + 3072;
        float* cm  = sA + 4096;
        float* Aw  = sA + 5120;
        float* Bc   = sB;               // [4][256]
        float* swq  = sB + 1024;        // 768
        float* kmx  = sB + 1792;        // [4]
        float* kmn  = sB + 1796;
        float* t25  = sB + 1800;        // [4]
        float* t26  = sB + 1804;
        float* thr  = sB + 1808;
        float* bias = sB + 1812;        // [4][3]
        float* red  = (float*)s4;       // 8192 floats

        if (t < 384) { swq[t] = wqkv[t]; swq[t + 384] = wqkv[t + 384]; }

        // reduce split-K partials -> sq/sk/sv
        #pragma unroll
        for (int m = 0; m < 3; ++m) {
            int b = t >> 7, c0 = (t & 127) * 2;
            float a0 = 0.f, a1 = 0.f;
            #pragma unroll 8
            for (int g = 0; g < 32; ++g) {
                float2 v = ld_wt2(part + (size_t)((m * 32 + g) * 4 + b) * 256 + c0);
                a0 += v.x; a1 += v.y;
            }
            float* dst = (m == 0) ? sq : (m == 1) ? sk : sv;
            dst[b * 256 + c0] = a0; dst[b * 256 + c0 + 1] = a1;
        }
        __syncthreads();

        // per-batch k max/min (exact rank-1 row max, like P3)
        if (t < 256) {
            int b = t >> 6, l = t & 63;
            float mx = -1e30f, mn = 1e30f;
            #pragma unroll
            for (int u = 0; u < 4; ++u) {
                float v = sk[b * 256 + l + u * 64];
                mx = fmaxf(mx, v); mn = fminf(mn, v);
            }
            #pragma unroll
            for (int m2 = 1; m2 < 64; m2 <<= 1) {
                mx = fmaxf(mx, __shfl_xor(mx, m2, 64));
                mn = fminf(mn, __shfl_xor(mn, m2, 64));
            }
            if (l == 0) { kmx[b] = mx; kmn[b] = mn; }
        }
        __syncthreads();

        // channel attention: 2 passes cover 4 batches; thread = (b, c)
        #pragma unroll
        for (int pp = 0; pp < 2; ++pp) {
            int b = pp * 2 + (t >> 8), c = t & 255;
            float a = sq[b * 256 + c];
            float m = (a >= 0.f) ? a * kmx[b] : a * kmn[b];
            float den = 0.f, num = 0.f;
            #pragma unroll 4
            for (int j = 0; j < 256; ++j) {
                float e = __expf(fmaf(a, sk[b * 256 + j], -m));
                den += e; num = fmaf(e, sv[b * 256 + j], num);
            }
            att[b * 256 + c] = num / den;
        }
        __syncthreads();

        // cm = sigmoid(att @ wp): rows split 8 ways, float4 cols, 4 batches
        {
            int rg = sub, c4 = lane * 4;
            float4 a0 = make_float4(0.f, 0.f, 0.f, 0.f);
            float4 a1 = a0, a2 = a0, a3 = a0;
            const float* wpp = wp + (size_t)rg * 32 * 256 + c4;
            #pragma unroll 8
            for (int i = 0; i < 32; ++i) {
                float4 w = *(const float4*)(wpp + (size_t)i * 256);
                int r = rg * 32 + i;
                float g0 = att[r], g1 = att[256 + r], g2 = att[512 + r], g3 = att[768 + r];
                a0.x = fmaf(g0, w.x, a0.x); a0.y = fmaf(g0, w.y, a0.y);
                a0.z = fmaf(g0, w.z, a0.z); a0.w = fmaf(g0, w.w, a0.w);
                a1.x = fmaf(g1, w.x, a1.x); a1.y = fmaf(g1, w.y, a1.y);
                a1.z = fmaf(g1, w.z, a1.z); a1.w = fmaf(g1, w.w, a1.w);
                a2.x = fmaf(g2, w.x, a2.x); a2.y = fmaf(g2, w.y, a2.y);
                a2.z = fmaf(g2, w.z, a2.z); a2.w = fmaf(g2, w.w, a2.w);
                a3.x = fmaf(g3, w.x, a3.x); a3.y = fmaf(g3, w.y, a3.y);
                a3.z = fmaf(g3, w.z, a3.z); a3.w = fmaf(g3, w.w, a3.w);
            }
            *(float4*)(red + (0 * 8 + rg) * 256 + c4) = a0;
            *(float4*)(red + (1 * 8 + rg) * 256 + c4) = a1;
            *(float4*)(red + (2 * 8 + rg) * 256 + c4) = a2;
            *(float4*)(red + (3 * 8 + rg) * 256 + c4) = a3;
        }
        __syncthreads();
        #pragma unroll
        for (int u = 0; u < 2; ++u) {
            int idx = t + u * 512;            // (b,c) over 1024
            int b = idx >> 8, c = idx & 255;
            float ac = 0.f;
            #pragma unroll
            for (int r = 0; r < 8; ++r) ac += red[(b * 8 + r) * 256 + c];
            cm[b * 256 + c] = 1.0f / (1.0f + __expf(-ac));
        }
        __syncthreads();

        // percentile per batch (linear, rank 25/26 of 256)
        #pragma unroll
        for (int u = 0; u < 2; ++u) {
            int idx = t + u * 512;
            int b = idx >> 8, c = idx & 255;
            float my = cm[b * 256 + c];
            int rank = 0;
            for (int j = 0; j < 256; ++j) {
                float o = cm[b * 256 + j];
                rank += (o < my) ? 1 : ((o == my && j < c) ? 1 : 0);
            }
            if (rank == 25) t25[b] = my;      // unique writers per batch
            if (rank == 26) t26[b] = my;
        }
        __syncthreads();
        if (t < 4) thr[t] = t25[t] + 0.5f * (t26[t] - t25[t]);
        __syncthreads();

        // fold affine A (LDS), Bc; bias = Bc @ w_qkv
        #pragma unroll
        for (int u = 0; u < 2; ++u) {
            int idx = t + u * 512;
            int b = idx >> 8, c = idx & 255;
            float s2 = bng[c] * rsqrtf(bnv[c] + EPS);
            float o2 = bnb[c] - bnm[c] * s2;
            float cc = cm[b * 256 + c];
            float pm = (cc > thr[b]) ? cc : 0.f;
            Aw[b * 256 + c] = (1.f + cc) * s2 * pm;
            Bc[b * 256 + c] = o2 * pm;
        }
        __syncthreads();
        if (t < 12) {
            int b = t >> 2;                   // t = b*... use (b,f) = (t/3, t%3)
            b = t / 3; int f = t - b * 3;
            float s3 = 0.f;
            for (int ch = 0; ch < 256; ++ch)
                s3 = fmaf(Bc[b * 256 + ch], swq[ch * 3 + f], s3);
            bias[b * 3 + f] = s3;
        }
        __syncthreads();

        // ================= P2: qkv = (x*A + B) @ w_qkv =================
        {
            float w00 = wAv.x, w01 = wAv.y, w02 = wAv.z;
            float w10 = wAv.w, w11 = wBv.x, w12 = wBv.y;
            float w20 = wBv.z, w21 = wBv.w, w22 = wCv.x;
            float w30 = wCv.y, w31 = wCv.z, w32 = wCv.w;
            int wid = blk * 8 + sub;          // 0..2047
            #pragma unroll
            for (int bb = 0; bb < 4; ++bb) {
                float4 A4 = *(const float4*)(Aw + bb * 256 + 4 * lane);
                float bq = bias[bb * 3 + 0];
                float bk = bias[bb * 3 + 1];
                float bv = bias[bb * 3 + 2];
                #pragma unroll
                for (int j = 0; j < 2; ++j) {
                    int pix = bb * 4096 + wid + j * 2048;
                    float4 xv = px[j][bb];
                    float t0 = xv.x * A4.x, t1 = xv.y * A4.y;
                    float t2 = xv.z * A4.z, t3 = xv.w * A4.w;
                    float q = t0 * w00 + t1 * w10 + t2 * w20 + t3 * w30;
                    float k = t0 * w01 + t1 * w11 + t2 * w21 + t3 * w31;
                    float v = t0 * w02 + t1 * w12 + t2 * w22 + t3 * w32;
                    #pragma unroll
                    for (int m2 = 1; m2 < 64; m2 <<= 1) {
                        q += __shfl_xor(q, m2, 64);
                        k += __shfl_xor(k, m2, 64);
                        v += __shfl_xor(v, m2, 64);
                    }
                    if (lane == 0) {
                        st_wt(qs + pix, q + bq);
                        st_wt(ks + pix, k + bk);
                        st_wt(vs + pix, v + bv);
                    }
                }
            }
        }
    }
    gridbar(base + 3);

    // ================= P3: spatial attention + output =================
    {
        float* pden = sA;            // [8][64]
        float* pnum = sA + 512;
        float* rmax = sB;
        float* rmin = sB + 8;
        int b = blk >> 6, ic = blk & 63;
        int base3 = b * 4096;
        float kmx = -1e30f, kmn = 1e30f;
        #pragma unroll
        for (int u = 0; u < 2; ++u) {
            int i = t + u * 512;              // float4 row index 0..1023
            float2 klo = ld_wt2(ks + base3 + i * 4);
            float2 khi = ld_wt2(ks + base3 + i * 4 + 2);
            float2 vlo = ld_wt2(vs + base3 + i * 4);
            float2 vhi = ld_wt2(vs + base3 + i * 4 + 2);
            s4[i * 2]     = make_float4(klo.x, vlo.x, klo.y, vlo.y);
            s4[i * 2 + 1] = make_float4(khi.x, vhi.x, khi.y, vhi.y);
            kmx = fmaxf(kmx, fmaxf(fmaxf(klo.x, klo.y), fmaxf(khi.x, khi.y)));
            kmn = fminf(kmn, fminf(fminf(klo.x, klo.y), fminf(khi.x, khi.y)));
        }
        #pragma unroll
        for (int m2 = 1; m2 < 64; m2 <<= 1) {
            kmx = fmaxf(kmx, __shfl_xor(kmx, m2, 64));
            kmn = fminf(kmn, __shfl_xor(kmn, m2, 64));
        }
        if (lane == 0) { rmax[sub] = kmx; rmin[sub] = kmn; }
        __syncthreads();
        float mx = rmax[0], mn = rmin[0];
        #pragma unroll
        for (int s = 1; s < 8; ++s) { mx = fmaxf(mx, rmax[s]); mn = fminf(mn, rmin[s]); }

        int row = ic * 64 + lane;
        float a = ld_wt(qs + base3 + row);
        float m = (a >= 0.f) ? a * mx : a * mn;   // exact global row max (rank-1)
        float den0 = 0.f, num0 = 0.f, den1 = 0.f, num1 = 0.f;
        const float4* sp = s4 + sub * 256;        // this wave's 512-j slice
        #pragma unroll 4
        for (int j = 0; j < 256; ++j) {
            float4 kv = sp[j];                    // uniform addr -> broadcast
            float e0 = __expf(fmaf(a, kv.x, -m));
            float e1 = __expf(fmaf(a, kv.z, -m));
            den0 += e0; num0 = fmaf(e0, kv.y, num0);
            den1 += e1; num1 = fmaf(e1, kv.w, num1);
        }
        pden[sub * 64 + lane] = den0 + den1;
        pnum[sub * 64 + lane] = num0 + num1;
        __syncthreads();
        if (t < 64) {
            float den = 0.f, num = 0.f;
            #pragma unroll
            for (int s = 0; s < 8; ++s) { den += pden[s * 64 + t]; num += pnum[s * 64 + t]; }
            int r = ic * 64 + t;
            float vrow = (r & 1) ? s4[r >> 1].w : s4[r >> 1].y;
            out[base3 + r] = vrow + num / den;
        }
    }
}

extern "C" void kernel_launch(void* const* d_in, const int* in_sizes, int n_in,
                              void* d_out, int out_size, void* d_ws, size_t ws_size,
                              hipStream_t stream) {
    const float* x    = (const float*)d_in[0];
    const float* cag  = (const float*)d_in[1];
    const float* cab  = (const float*)d_in[2];
    const float* cam  = (const float*)d_in[3];
    const float* cav  = (const float*)d_in[4];
    const float* wq   = (const float*)d_in[5];
    const float* wk   = (const float*)d_in[6];
    const float* wv   = (const float*)d_in[7];
    const float* wp   = (const float*)d_in[8];
    const float* bng  = (const float*)d_in[9];
    const float* bnb  = (const float*)d_in[10];
    const float* bnm  = (const float*)d_in[11];
    const float* bnv  = (const float*)d_in[12];
    const float* wqkv = (const float*)d_in[13];

    float* ws = (float*)d_ws;
    mega<<<dim3(256), dim3(512), 0, stream>>>(x, cag, cab, cam, cav,
                                              wq, wk, wv, wp,
                                              bng, bnb, bnm, bnv, wqkv,
                                              ws, (float*)d_out);
}

// Round 5
// 143.063 us; speedup vs baseline: 1.9510x; 1.1503x over previous
//
#include <hip/hip_runtime.h>

#define EPS 1e-3f
#define NBLK 256

// ---- ws layout (float offsets; 1KB guard gaps between regions) ----
#define OFF_PGAP   0         // 65536  : gap partials [256 blk][256 ch]
#define OFF_PART   66560     // 98304  : qkv split-K partials [3][32][4][256]
#define OFF_AW     165888    // 1024   : folded affine A [4][256]
#define OFF_BIAS   166912    // 16     : folded qkv bias [4][3]
#define OFF_QS     167936    // 16384  : spatial q [4][4096]
#define OFF_KS     185344    // 16384  : spatial k
#define OFF_VS     202752    // 16384  : spatial v

// ---- agent-scope (coherence-point, L2-bypass) helpers: NO cache-maintenance ----
__device__ __forceinline__ void st_wt(float* p, float v) {
    __hip_atomic_store(p, v, __ATOMIC_RELAXED, __HIP_MEMORY_SCOPE_AGENT);
}
__device__ __forceinline__ void st_wt2(float* p, float a, float b) {
    union { float f[2]; unsigned long long u; } x; x.f[0] = a; x.f[1] = b;
    __hip_atomic_store((unsigned long long*)p, x.u, __ATOMIC_RELAXED,
                       __HIP_MEMORY_SCOPE_AGENT);
}
__device__ __forceinline__ float ld_wt(const float* p) {
    return __hip_atomic_load(p, __ATOMIC_RELAXED, __HIP_MEMORY_SCOPE_AGENT);
}
__device__ __forceinline__ float2 ld_wt2(const float* p) {
    union { unsigned long long u; float f[2]; } x;
    x.u = __hip_atomic_load((const unsigned long long*)p, __ATOMIC_RELAXED,
                            __HIP_MEMORY_SCOPE_AGENT);
    return make_float2(x.f[0], x.f[1]);
}

// ---- pure flag-array grid barrier: zero fences, zero invalidates ----
// Visibility contract: all cross-block traffic uses agent-scope WT helpers,
// so data is at the coherence point once vmcnt drains (guaranteed by the
// pre-barrier __syncthreads + release flag store).
__device__ unsigned g_flags[NBLK * 32];   // 128B stride, one line per block
__device__ unsigned g_release;

__device__ __forceinline__ void gridbar(unsigned epoch) {
    __syncthreads();                 // drains every wave's vmcnt
    int t = threadIdx.x, blk = blockIdx.x;
    if (blk == 0) {
        if (t == 0)
            __hip_atomic_store(&g_flags[0], epoch, __ATOMIC_RELEASE,
                               __HIP_MEMORY_SCOPE_AGENT);
        if (t > 0 && t < NBLK) {
            unsigned tries = 0;
            while (__hip_atomic_load(&g_flags[t * 32], __ATOMIC_RELAXED,
                                     __HIP_MEMORY_SCOPE_AGENT) < epoch) {
                __builtin_amdgcn_s_sleep(1);
                if (++tries > 8000000u) break;     // hang safety valve
            }
        }
        __syncthreads();
        if (t == 0)
            __hip_atomic_store(&g_release, epoch, __ATOMIC_RELEASE,
                               __HIP_MEMORY_SCOPE_AGENT);
        __syncthreads();
    } else {
        if (t == 0) {
            __hip_atomic_store(&g_flags[blk * 32], epoch, __ATOMIC_RELEASE,
                               __HIP_MEMORY_SCOPE_AGENT);
            unsigned tries = 0;
            while (__hip_atomic_load(&g_release, __ATOMIC_RELAXED,
                                     __HIP_MEMORY_SCOPE_AGENT) < epoch) {
                __builtin_amdgcn_s_sleep(1);
                if (++tries > 8000000u) break;     // hang safety valve
            }
        }
        __syncthreads();
    }
}

// Persistent kernel, 256 blocks x 512 threads, 4 grid barriers.
// P0 : gap partials (all blocks) + weight L3 warm            -> pgap (WT)
// P1a: split-K qkv matmul, 96 blocks (3 mats x 32 rowgroups) -> part (WT)
// P1c: NARROW tail, blocks 0-3 (one per batch): reduce own batch's part slice,
//      channel softmax (exact rank-1 max), wp matvec, percentile, fold
//      -> Aw[4][256], bias[4][3] (WT, 4KB)
// P2 : qkv = (x*A + B) @ w_qkv, wave per pixel               -> qs/ks/vs (WT)
// P3 : spatial attention + output
__global__ __launch_bounds__(512) void mega(
    const float* __restrict__ x,
    const float* __restrict__ cag, const float* __restrict__ cab,
    const float* __restrict__ cam, const float* __restrict__ cav,
    const float* __restrict__ wq, const float* __restrict__ wk,
    const float* __restrict__ wv, const float* __restrict__ wp,
    const float* __restrict__ bng, const float* __restrict__ bnb,
    const float* __restrict__ bnm, const float* __restrict__ bnv,
    const float* __restrict__ wqkv,
    float* __restrict__ ws, float* __restrict__ out)
{
    __shared__ float4 s4[2048];   // 32KB: P0 partials / P3 skv
    __shared__ float  sA[6144];   // 24KB: P1a red / P1c vectors / P3 pden,pnum
    __shared__ float  sB[2576];   // 10KB: P1a gpart,gn / P1c swq,Bc,scalars / P3 rmax,rmin
    __shared__ unsigned sBase;

    float* pgap  = ws + OFF_PGAP;
    float* part  = ws + OFF_PART;
    float* Aw    = ws + OFF_AW;
    float* biasW = ws + OFF_BIAS;
    float* qs    = ws + OFF_QS;
    float* ks    = ws + OFF_KS;
    float* vs    = ws + OFF_VS;

    int blk = blockIdx.x;             // 0..255
    int t = threadIdx.x;              // 0..511
    int lane = t & 63, sub = t >> 6;  // sub = wave id (wave-uniform)

    if (t == 0)
        sBase = __hip_atomic_load(&g_release, __ATOMIC_RELAXED,
                                  __HIP_MEMORY_SCOPE_AGENT);

    // ================= P0: gap partials + L3 warm =================
    {
        if (t < 256) {   // 4KB weight slice per block -> wq/wk/wv/wp into L3
            const float* wmat = (blk < 64) ? wq : (blk < 128) ? wk
                              : (blk < 192) ? wv : wp;
            float4 w4 = *(const float4*)(wmat + (size_t)(blk & 63) * 1024 + 4 * t);
            asm volatile("" :: "v"(w4.x), "v"(w4.y), "v"(w4.z), "v"(w4.w));
        }
        if (blk == 1 && t < 256) {
            float z = bng[t] + bnb[t] + bnm[t] + bnv[t];
            asm volatile("" :: "v"(z));
        }
        if (blk == 2 && t < 256) {
            float z = cag[t] + cab[t] + cam[t] + cav[t];
            asm volatile("" :: "v"(z));
        }
        const float* xp = x + ((size_t)blk * 64 + sub * 8) * 256 + 4 * lane;
        float4 s = make_float4(0.f, 0.f, 0.f, 0.f);
        #pragma unroll
        for (int u = 0; u < 8; ++u) {
            float4 v = *(const float4*)(xp + (size_t)u * 256);
            s.x += v.x; s.y += v.y; s.z += v.z; s.w += v.w;
        }
        s4[sub * 64 + lane] = s;
        __syncthreads();              // also publishes sBase
        if (t < 64) {
            float4 o = s4[t];
            #pragma unroll
            for (int p = 1; p < 8; ++p) {
                float4 v = s4[p * 64 + t];
                o.x += v.x; o.y += v.y; o.z += v.z; o.w += v.w;
            }
            st_wt2(pgap + blk * 256 + 4 * t,     o.x, o.y);
            st_wt2(pgap + blk * 256 + 4 * t + 2, o.z, o.w);
        }
    }
    unsigned base = sBase;
    gridbar(base + 1);

    // Prefetch this wave's P2 x tiles (L3-resident after P0) + wqkv rows.
    float4 px[2][4];
    #pragma unroll
    for (int j = 0; j < 2; ++j)
        #pragma unroll
        for (int bb = 0; bb < 4; ++bb)
            px[j][bb] = *(const float4*)(
                x + (size_t)(bb * 4096 + blk * 8 + sub + j * 2048) * 256 + 4 * lane);
    float4 wAv = *(const float4*)(wqkv + 12 * lane);
    float4 wBv = *(const float4*)(wqkv + 12 * lane + 4);
    float4 wCv = *(const float4*)(wqkv + 12 * lane + 8);

    // ================= P1a: split-K qkv matmul (96 blocks) =================
    if (blk < 96) {
        int m = blk / 32, g = blk % 32;       // matrix, rowgroup
        int r0 = g * 8;
        const float* W = (m == 0) ? wq : (m == 1) ? wk : wv;
        float* gpart = sB;                    // [4][8][16]
        float* gn_s  = sB + 512;              // [4][8]

        {   // gn for rows r0..r0+7, 4 batches: 512 workers = (b, row, p4)
            int b = t >> 7, row = (t >> 4) & 7, p4 = t & 15;
            float s = 0.f;
            #pragma unroll
            for (int q = 0; q < 4; ++q)
                s += ld_wt(pgap + (size_t)(b * 64 + p4 * 4 + q) * 256 + r0 + row);
            gpart[b * 128 + row * 16 + p4] = s;
        }
        __syncthreads();
        if (t < 32) {
            int b = t >> 3, row = t & 7;
            float s = 0.f;
            #pragma unroll
            for (int p = 0; p < 16; ++p) s += gpart[b * 128 + row * 16 + p];
            float gv = s * (1.0f / 4096.0f);
            int c = r0 + row;
            float sc = cag[c] * rsqrtf(cav[c] + EPS);
            gn_s[b * 8 + row] = gv * sc + (cab[c] - cam[c] * sc);
        }
        __syncthreads();
        {   // rows split h=t>>8 (4 rows each), col c=t&255, coalesced W loads
            int c = t & 255, h = t >> 8;
            float a0 = 0.f, a1 = 0.f, a2 = 0.f, a3 = 0.f;
            #pragma unroll
            for (int rr = 0; rr < 4; ++rr) {
                int ri = h * 4 + rr;
                float w = W[(size_t)(r0 + ri) * 256 + c];
                a0 = fmaf(gn_s[0 * 8 + ri], w, a0);
                a1 = fmaf(gn_s[1 * 8 + ri], w, a1);
                a2 = fmaf(gn_s[2 * 8 + ri], w, a2);
                a3 = fmaf(gn_s[3 * 8 + ri], w, a3);
            }
            sA[(h * 4 + 0) * 256 + c] = a0;
            sA[(h * 4 + 1) * 256 + c] = a1;
            sA[(h * 4 + 2) * 256 + c] = a2;
            sA[(h * 4 + 3) * 256 + c] = a3;
        }
        __syncthreads();
        {   // combine halves, WT-store partials [m][g][b][c]
            int b = t >> 7, c0 = (t & 127) * 2;
            float v0 = sA[b * 256 + c0]     + sA[(4 + b) * 256 + c0];
            float v1 = sA[b * 256 + c0 + 1] + sA[(4 + b) * 256 + c0 + 1];
            st_wt2(part + (size_t)((m * 32 + g) * 4 + b) * 256 + c0, v0, v1);
        }
    }
    gridbar(base + 2);

    // ====== P1c: narrow tail, blocks 0-3 (one per batch) ======
    if (blk < 4) {
        int b = blk;
        float* sq  = sA;               // [256]
        float* sk  = sA + 256;
        float* sv  = sA + 512;
        float* att = sA + 768;
        float* cmv = sA + 1024;
        float* red = sA + 1280;        // 2048 scratch (softmax halves / wp partials)
        float* swq = sB;               // 768
        float* sc2 = sB + 768;         // [0]=kmx [1]=kmn [2]=t25 [3]=t26 [4]=thr
        float* Bc  = sB + 800;         // 256

        if (t < 384) { swq[t] = wqkv[t]; swq[t + 384] = wqkv[t + 384]; }

        // reduce this batch's part slice -> sq/sk/sv (98KB, float2 loads)
        if (t < 384) {
            int m = t >> 7, c0 = (t & 127) * 2;
            float a0 = 0.f, a1 = 0.f;
            #pragma unroll 8
            for (int g = 0; g < 32; ++g) {
                float2 v = ld_wt2(part + (size_t)((m * 32 + g) * 4 + b) * 256 + c0);
                a0 += v.x; a1 += v.y;
            }
            float* dst = (m == 0) ? sq : (m == 1) ? sk : sv;
            dst[c0] = a0; dst[c0 + 1] = a1;
        }
        __syncthreads();

        // k max/min (exact rank-1 row max)
        if (t < 64) {
            float mx = -1e30f, mn = 1e30f;
            #pragma unroll
            for (int u = 0; u < 4; ++u) {
                float v = sk[t + u * 64];
                mx = fmaxf(mx, v); mn = fminf(mn, v);
            }
            #pragma unroll
            for (int m2 = 1; m2 < 64; m2 <<= 1) {
                mx = fmaxf(mx, __shfl_xor(mx, m2, 64));
                mn = fminf(mn, __shfl_xor(mn, m2, 64));
            }
            if (t == 0) { sc2[0] = mx; sc2[1] = mn; }
        }
        __syncthreads();

        // channel softmax: c = t&255, h = t>>8 covers a 128-j half
        {
            int c = t & 255, h = t >> 8;
            float a = sq[c];
            float m = (a >= 0.f) ? a * sc2[0] : a * sc2[1];
            const float* skp = sk + h * 128;
            const float* svp = sv + h * 128;
            float den = 0.f, num = 0.f;
            #pragma unroll 4
            for (int j = 0; j < 128; ++j) {
                float e = __expf(fmaf(a, skp[j], -m));
                den += e; num = fmaf(e, svp[j], num);
            }
            red[h * 256 + c] = den;
            red[512 + h * 256 + c] = num;
        }
        __syncthreads();
        if (t < 256)
            att[t] = (red[512 + t] + red[768 + t]) / (red[t] + red[256 + t]);
        __syncthreads();

        // cm = sigmoid(att @ wp): 8-way row split, float4 cols (wp L3-warm)
        {
            int rg = sub, c4 = lane * 4;
            float4 ac = make_float4(0.f, 0.f, 0.f, 0.f);
            const float* wpp = wp + (size_t)rg * 32 * 256 + c4;
            #pragma unroll 8
            for (int i = 0; i < 32; ++i) {
                float g = att[rg * 32 + i];
                float4 w = *(const float4*)(wpp + (size_t)i * 256);
                ac.x = fmaf(g, w.x, ac.x); ac.y = fmaf(g, w.y, ac.y);
                ac.z = fmaf(g, w.z, ac.z); ac.w = fmaf(g, w.w, ac.w);
            }
            *(float4*)(red + rg * 256 + c4) = ac;
        }
        __syncthreads();
        if (t < 256) {
            float ac = 0.f;
            #pragma unroll
            for (int r = 0; r < 8; ++r) ac += red[r * 256 + t];
            cmv[t] = 1.0f / (1.0f + __expf(-ac));
        }
        __syncthreads();

        // 10th percentile (linear): s[25] + 0.5*(s[26]-s[25])
        if (t < 256) {
            float my = cmv[t];
            int rank = 0;
            for (int j = 0; j < 256; ++j) {
                float o = cmv[j];
                rank += (o < my) ? 1 : ((o == my && j < t) ? 1 : 0);
            }
            if (rank == 25) sc2[2] = my;     // unique writers (ranks = permutation)
            if (rank == 26) sc2[3] = my;
        }
        __syncthreads();
        if (t == 0) sc2[4] = sc2[2] + 0.5f * (sc2[3] - sc2[2]);
        __syncthreads();

        // fold affine A, Bc; bias = Bc @ w_qkv ; WT-publish
        if (t < 256) {
            float s2 = bng[t] * rsqrtf(bnv[t] + EPS);
            float o2 = bnb[t] - bnm[t] * s2;
            float cc = cmv[t];
            float pm = (cc > sc2[4]) ? cc : 0.f;
            st_wt(Aw + b * 256 + t, (1.f + cc) * s2 * pm);
            Bc[t] = o2 * pm;
        }
        __syncthreads();
        if (t < 3) {
            float s3 = 0.f;
            for (int ch = 0; ch < 256; ++ch)
                s3 = fmaf(Bc[ch], swq[ch * 3 + t], s3);
            st_wt(biasW + b * 3 + t, s3);
        }
    }
    gridbar(base + 3);

    // ================= P2: qkv = (x*A + B) @ w_qkv =================
    {
        float w00 = wAv.x, w01 = wAv.y, w02 = wAv.z;
        float w10 = wAv.w, w11 = wBv.x, w12 = wBv.y;
        float w20 = wBv.z, w21 = wBv.w, w22 = wCv.x;
        float w30 = wCv.y, w31 = wCv.z, w32 = wCv.w;
        int wid = blk * 8 + sub;          // 0..2047
        #pragma unroll
        for (int bb = 0; bb < 4; ++bb) {
            float2 alo = ld_wt2(Aw + bb * 256 + 4 * lane);
            float2 ahi = ld_wt2(Aw + bb * 256 + 4 * lane + 2);
            float bq = ld_wt(biasW + bb * 3 + 0);
            float bk = ld_wt(biasW + bb * 3 + 1);
            float bv = ld_wt(biasW + bb * 3 + 2);
            #pragma unroll
            for (int j = 0; j < 2; ++j) {
                int pix = bb * 4096 + wid + j * 2048;
                float4 xv = px[j][bb];
                float t0 = xv.x * alo.x, t1 = xv.y * alo.y;
                float t2 = xv.z * ahi.x, t3 = xv.w * ahi.y;
                float q = t0 * w00 + t1 * w10 + t2 * w20 + t3 * w30;
                float k = t0 * w01 + t1 * w11 + t2 * w21 + t3 * w31;
                float v = t0 * w02 + t1 * w12 + t2 * w22 + t3 * w32;
                #pragma unroll
                for (int m2 = 1; m2 < 64; m2 <<= 1) {
                    q += __shfl_xor(q, m2, 64);
                    k += __shfl_xor(k, m2, 64);
                    v += __shfl_xor(v, m2, 64);
                }
                if (lane == 0) {
                    st_wt(qs + pix, q + bq);
                    st_wt(ks + pix, k + bk);
                    st_wt(vs + pix, v + bv);
                }
            }
        }
    }
    gridbar(base + 4);

    // ================= P3: spatial attention + output =================
    {
        float* pden = sA;            // [8][64]
        float* pnum = sA + 512;
        float* rmax = sB;
        float* rmin = sB + 8;
        int b = blk >> 6, ic = blk & 63;
        int base3 = b * 4096;
        float kmx = -1e30f, kmn = 1e30f;
        #pragma unroll
        for (int u = 0; u < 2; ++u) {
            int i = t + u * 512;              // float4 row index 0..1023
            float2 klo = ld_wt2(ks + base3 + i * 4);
            float2 khi = ld_wt2(ks + base3 + i * 4 + 2);
            float2 vlo = ld_wt2(vs + base3 + i * 4);
            float2 vhi = ld_wt2(vs + base3 + i * 4 + 2);
            s4[i * 2]     = make_float4(klo.x, vlo.x, klo.y, vlo.y);
            s4[i * 2 + 1] = make_float4(khi.x, vhi.x, khi.y, vhi.y);
            kmx = fmaxf(kmx, fmaxf(fmaxf(klo.x, klo.y), fmaxf(khi.x, khi.y)));
            kmn = fminf(kmn, fminf(fminf(klo.x, klo.y), fminf(khi.x, khi.y)));
        }
        #pragma unroll
        for (int m2 = 1; m2 < 64; m2 <<= 1) {
            kmx = fmaxf(kmx, __shfl_xor(kmx, m2, 64));
            kmn = fminf(kmn, __shfl_xor(kmn, m2, 64));
        }
        if (lane == 0) { rmax[sub] = kmx; rmin[sub] = kmn; }
        __syncthreads();
        float mx = rmax[0], mn = rmin[0];
        #pragma unroll
        for (int s = 1; s < 8; ++s) { mx = fmaxf(mx, rmax[s]); mn = fminf(mn, rmin[s]); }

        int row = ic * 64 + lane;
        float a = ld_wt(qs + base3 + row);
        float m = (a >= 0.f) ? a * mx : a * mn;   // exact global row max (rank-1)
        float den0 = 0.f, num0 = 0.f, den1 = 0.f, num1 = 0.f;
        const float4* sp = s4 + sub * 256;        // this wave's 512-j slice
        #pragma unroll 4
        for (int j = 0; j < 256; ++j) {
            float4 kv = sp[j];                    // uniform addr -> broadcast
            float e0 = __expf(fmaf(a, kv.x, -m));
            float e1 = __expf(fmaf(a, kv.z, -m));
            den0 += e0; num0 = fmaf(e0, kv.y, num0);
            den1 += e1; num1 = fmaf(e1, kv.w, num1);
        }
        pden[sub * 64 + lane] = den0 + den1;
        pnum[sub * 64 + lane] = num0 + num1;
        __syncthreads();
        if (t < 64) {
            float den = 0.f, num = 0.f;
            #pragma unroll
            for (int s = 0; s < 8; ++s) { den += pden[s * 64 + t]; num += pnum[s * 64 + t]; }
            int r = ic * 64 + t;
            float vrow = (r & 1) ? s4[r >> 1].w : s4[r >> 1].y;
            out[base3 + r] = vrow + num / den;
        }
    }
}

extern "C" void kernel_launch(void* const* d_in, const int* in_sizes, int n_in,
                              void* d_out, int out_size, void* d_ws, size_t ws_size,
                              hipStream_t stream) {
    const float* x    = (const float*)d_in[0];
    const float* cag  = (const float*)d_in[1];
    const float* cab  = (const float*)d_in[2];
    const float* cam  = (const float*)d_in[3];
    const float* cav  = (const float*)d_in[4];
    const float* wq   = (const float*)d_in[5];
    const float* wk   = (const float*)d_in[6];
    const float* wv   = (const float*)d_in[7];
    const float* wp   = (const float*)d_in[8];
    const float* bng  = (const float*)d_in[9];
    const float* bnb  = (const float*)d_in[10];
    const float* bnm  = (const float*)d_in[11];
    const float* bnv  = (const float*)d_in[12];
    const float* wqkv = (const float*)d_in[13];

    float* ws = (float*)d_ws;
    mega<<<dim3(256), dim3(512), 0, stream>>>(x, cag, cab, cam, cav,
                                              wq, wk, wv, wp,
                                              bng, bnb, bnm, bnv, wqkv,
                                              ws, (float*)d_out);
}